// Round 3
// baseline (204.236 us; speedup 1.0000x reference)
//
#include <hip/hip_runtime.h>

typedef __bf16 bf16_t;
typedef bf16_t bf16x8 __attribute__((ext_vector_type(8)));
typedef float f32x4 __attribute__((ext_vector_type(4)));

#define MFMA(a,b,c) __builtin_amdgcn_mfma_f32_16x16x32_bf16(a,b,c,0,0,0)

__device__ __forceinline__ void split8(float4 a, float4 b, bf16x8& hi, bf16x8& lo){
  float v[8] = {a.x,a.y,a.z,a.w,b.x,b.y,b.z,b.w};
  #pragma unroll
  for (int i=0;i<8;++i){
    bf16_t h = (bf16_t)v[i];
    hi[i] = h;
    lo[i] = (bf16_t)(v[i] - (float)h);
  }
}

// Stage rows x 256 f32 -> LDS bf16 hi+lo, [row][256], per-row XOR swizzle on
// 16B chunks: chunk' = chunk ^ (row&7). Row pitch 512B.
template<int NT>
__device__ __forceinline__ void stage_split(const float* __restrict__ src,
                                            char* dstH, char* dstL, int rows, int tid){
  const int nchunk = rows * 32;
  const float4* s4 = reinterpret_cast<const float4*>(src);
  for (int cid = tid; cid < nchunk; cid += NT){
    int r = cid >> 5, c = cid & 31;
    bf16x8 hi, lo;
    split8(s4[cid*2], s4[cid*2+1], hi, lo);
    int off = r*512 + ((c ^ (r&7))<<4);
    *reinterpret_cast<bf16x8*>(dstH + off) = hi;
    *reinterpret_cast<bf16x8*>(dstL + off) = lo;
  }
}

__device__ __forceinline__ bf16x8 ldsA(const char* buf, int row, int c16){
  return *reinterpret_cast<const bf16x8*>(buf + row*512 + ((c16 ^ (row&7))<<4));
}

// 64x64 C tile: C = A * W^T, K=256, split precision on BOTH operands:
// acc += Ah*Bh + Ah*Bl + Al*Bh  (error ~2^-17 per product)
__device__ __forceinline__ void gemm_split(f32x4 acc[4][4], const char* bufH,
    const char* bufL, const float* __restrict__ W, int m0, int n0, int lo16, int hi4){
  for (int kb = 0; kb < 8; ++kb){
    bf16x8 ah[4], al[4], bh[4], bl[4];
    #pragma unroll
    for (int mb = 0; mb < 4; ++mb){
      ah[mb] = ldsA(bufH, m0 + mb*16 + lo16, kb*4 + hi4);
      al[mb] = ldsA(bufL, m0 + mb*16 + lo16, kb*4 + hi4);
    }
    #pragma unroll
    for (int nb = 0; nb < 4; ++nb){
      const float4* p = reinterpret_cast<const float4*>(W + ((n0 + nb*16 + lo16)<<8) + kb*32 + hi4*8);
      split8(p[0], p[1], bh[nb], bl[nb]);
    }
    #pragma unroll
    for (int mb = 0; mb < 4; ++mb){
      #pragma unroll
      for (int nb = 0; nb < 4; ++nb){
        acc[mb][nb] = MFMA(ah[mb], bh[nb], acc[mb][nb]);
        acc[mb][nb] = MFMA(ah[mb], bl[nb], acc[mb][nb]);
        acc[mb][nb] = MFMA(al[mb], bh[nb], acc[mb][nb]);
      }
    }
  }
}

// single-precision (bf16) variant — used only for the scores GEMM
__device__ __forceinline__ void gemm_single(f32x4 acc[4][4], const char* bufH,
    const float* __restrict__ W, int m0, int n0, int lo16, int hi4){
  for (int kb = 0; kb < 8; ++kb){
    bf16x8 af[4], bfr[4];
    #pragma unroll
    for (int mb = 0; mb < 4; ++mb) af[mb] = ldsA(bufH, m0 + mb*16 + lo16, kb*4 + hi4);
    #pragma unroll
    for (int nb = 0; nb < 4; ++nb){
      const float4* p = reinterpret_cast<const float4*>(W + ((n0 + nb*16 + lo16)<<8) + kb*32 + hi4*8);
      bf16x8 hi, lo;
      split8(p[0], p[1], hi, lo);
      bfr[nb] = hi;
    }
    #pragma unroll
    for (int mb = 0; mb < 4; ++mb){
      #pragma unroll
      for (int nb = 0; nb < 4; ++nb) acc[mb][nb] = MFMA(af[mb], bfr[nb], acc[mb][nb]);
    }
  }
}

// ---------------------------------------------------------------------------
// k2_fused: per (expert e, 128-row batch tile):
//   h = x@W1[e]^T + b1 ; LN ; relu -> hr ; eo = hr@W2[e]^T + b2 -> global+LDS
//   k = eo@Wk^T + bk ; scores[b,n,e] = q[b,n*64:].k
// grid (2,256), block 512 (8 waves: wm in {0,1}, wn=head in {0..3})
// ---------------------------------------------------------------------------
__global__ __launch_bounds__(512, 2)
void k2_fused(const float* __restrict__ x, const float* __restrict__ W1,
              const float* __restrict__ b1, const float* __restrict__ g1,
              const float* __restrict__ bb1, const float* __restrict__ W2,
              const float* __restrict__ b2, const float* __restrict__ ipw,
              const float* __restrict__ ipb, const float* __restrict__ q,
              float* __restrict__ eo_out, float* __restrict__ scores)
{
  __shared__ char lds[136192];
  char* bufH = lds;                    // 64KB: x_hi -> hr_hi -> eo(bf16)
  char* bufL = lds + 65536;            // 64KB: x_lo -> hr_lo
  float* red = (float*)(lds + 131072); // [128][8]
  float* st  = (float*)(lds + 135168); // [128][2]

  const int e  = blockIdx.y;
  const int b0 = blockIdx.x * 128;
  const int tid = threadIdx.x;
  const int lane = tid & 63, wid = tid >> 6;
  const int lo16 = lane & 15, hi4 = lane >> 4;
  const int wm = wid >> 2, wn = wid & 3;
  const int m0 = wm * 64, n0 = wn * 64;

  stage_split<512>(x + b0*256, bufH, bufL, 128, tid);
  __syncthreads();

  f32x4 acc[4][4];
  #pragma unroll
  for (int mb=0;mb<4;++mb){
    #pragma unroll
    for (int nb=0;nb<4;++nb) acc[mb][nb] = (f32x4)0.0f;
  }

  gemm_split(acc, bufH, bufL, W1 + e*65536, m0, n0, lo16, hi4);

  float b1v[4], g1v[4], bbv[4];
  #pragma unroll
  for (int nb=0;nb<4;++nb){
    int c = n0 + nb*16 + lo16;
    b1v[nb] = b1[e*256 + c];
    g1v[nb] = g1[e*256 + c];
    bbv[nb] = bb1[e*256 + c];
  }
  #pragma unroll
  for (int mb=0;mb<4;++mb){
    #pragma unroll
    for (int nb=0;nb<4;++nb){
      #pragma unroll
      for (int r=0;r<4;++r) acc[mb][nb][r] += b1v[nb];
    }
  }

  // LN stats: per-row sum/sumsq across the 4 column-waves
  #pragma unroll
  for (int mb=0;mb<4;++mb){
    #pragma unroll
    for (int r=0;r<4;++r){
      float s=0.f, ss=0.f;
      #pragma unroll
      for (int nb=0;nb<4;++nb){ float v = acc[mb][nb][r]; s += v; ss += v*v; }
      #pragma unroll
      for (int m=1;m<16;m<<=1){ s += __shfl_xor(s, m, 64); ss += __shfl_xor(ss, m, 64); }
      if (lo16 == 0){
        int row = m0 + mb*16 + hi4*4 + r;
        red[row*8 + wn]     = s;
        red[row*8 + 4 + wn] = ss;
      }
    }
  }
  __syncthreads();   // also: all waves done reading x from bufH/bufL
  if (tid < 128){
    float s  = red[tid*8+0]+red[tid*8+1]+red[tid*8+2]+red[tid*8+3];
    float ss = red[tid*8+4]+red[tid*8+5]+red[tid*8+6]+red[tid*8+7];
    float mu = s * (1.f/256.f);
    float var = ss * (1.f/256.f) - mu*mu;
    st[tid*2]   = mu;
    st[tid*2+1] = rsqrtf(var + 1e-5f);
  }
  __syncthreads();

  // LN + relu -> hr (split bf16) into bufH/bufL
  #pragma unroll
  for (int mb=0;mb<4;++mb){
    #pragma unroll
    for (int r=0;r<4;++r){
      int row = m0 + mb*16 + hi4*4 + r;
      float mu = st[row*2], rs = st[row*2+1];
      #pragma unroll
      for (int nb=0;nb<4;++nb){
        int c = n0 + nb*16 + lo16;
        float v = (acc[mb][nb][r] - mu) * rs * g1v[nb] + bbv[nb];
        v = fmaxf(v, 0.f);
        int off = row*512 + (((c>>3) ^ (row&7))<<4) + (c&7)*2;
        bf16_t h = (bf16_t)v;
        *reinterpret_cast<bf16_t*>(bufH + off) = h;
        *reinterpret_cast<bf16_t*>(bufL + off) = (bf16_t)(v - (float)h);
      }
    }
  }
  __syncthreads();

  // GEMM2: eo = hr @ W2[e]^T + b2
  #pragma unroll
  for (int mb=0;mb<4;++mb){
    #pragma unroll
    for (int nb=0;nb<4;++nb) acc[mb][nb] = (f32x4)0.0f;
  }
  gemm_split(acc, bufH, bufL, W2 + e*65536, m0, n0, lo16, hi4);

  float b2v[4];
  #pragma unroll
  for (int nb=0;nb<4;++nb) b2v[nb] = b2[e*256 + n0 + nb*16 + lo16];

  __syncthreads();  // all waves done reading hr before eo overwrites bufH

  #pragma unroll
  for (int mb=0;mb<4;++mb){
    #pragma unroll
    for (int r=0;r<4;++r){
      int row = m0 + mb*16 + hi4*4 + r;
      int b = b0 + row;
      #pragma unroll
      for (int nb=0;nb<4;++nb){
        int c = n0 + nb*16 + lo16;
        float v = acc[mb][nb][r] + b2v[nb];
        eo_out[(b*256 + e)*256 + c] = v;
        int off = row*512 + (((c>>3) ^ (row&7))<<4) + (c&7)*2;
        *reinterpret_cast<bf16_t*>(bufH + off) = (bf16_t)v;
      }
    }
  }
  __syncthreads();

  // GEMM3: k = eo @ Wk^T + bk ; scores = q . k  (single precision is plenty)
  #pragma unroll
  for (int mb=0;mb<4;++mb){
    #pragma unroll
    for (int nb=0;nb<4;++nb) acc[mb][nb] = (f32x4)0.0f;
  }
  gemm_single(acc, bufH, ipw + 65536, m0, n0, lo16, hi4);

  float bkv[4];
  #pragma unroll
  for (int nb=0;nb<4;++nb) bkv[nb] = ipb[256 + n0 + nb*16 + lo16];

  #pragma unroll
  for (int mb=0;mb<4;++mb){
    #pragma unroll
    for (int r=0;r<4;++r){
      int row = m0 + mb*16 + hi4*4 + r;
      int b = b0 + row;
      float p = 0.f;
      #pragma unroll
      for (int nb=0;nb<4;++nb){
        int c = n0 + nb*16 + lo16;
        p += q[b*256 + c] * (acc[mb][nb][r] + bkv[nb]);
      }
      #pragma unroll
      for (int m=1;m<16;m<<=1) p += __shfl_xor(p, m, 64);
      if (lo16 == 0) scores[(b*4 + wn)*256 + e] = p;
    }
  }
}

// ---------------------------------------------------------------------------
// k_mini: out = act( maybeLN( (A @ W^T + bias) * scale ) ), 256x256x256,
// split-precision GEMM. grid 2, block 512.
// ---------------------------------------------------------------------------
__global__ __launch_bounds__(512, 2)
void k_mini(const float* __restrict__ A, const float* __restrict__ W,
            const float* __restrict__ bias, float scale, int do_ln,
            const float* __restrict__ g, const float* __restrict__ bb,
            int do_relu, float* __restrict__ out)
{
  __shared__ char lds[136192];
  char* bufH = lds;
  char* bufL = lds + 65536;
  float* red = (float*)(lds + 131072);
  float* st  = (float*)(lds + 135168);

  const int b0 = blockIdx.x * 128;
  const int tid = threadIdx.x;
  const int lane = tid & 63, wid = tid >> 6;
  const int lo16 = lane & 15, hi4 = lane >> 4;
  const int wm = wid >> 2, wn = wid & 3;
  const int m0 = wm * 64, n0 = wn * 64;

  stage_split<512>(A + b0*256, bufH, bufL, 128, tid);
  __syncthreads();

  f32x4 acc[4][4];
  #pragma unroll
  for (int mb=0;mb<4;++mb){
    #pragma unroll
    for (int nb=0;nb<4;++nb) acc[mb][nb] = (f32x4)0.0f;
  }
  gemm_split(acc, bufH, bufL, W, m0, n0, lo16, hi4);

  float bv[4], gv[4], bbv[4];
  #pragma unroll
  for (int nb=0;nb<4;++nb){
    int c = n0 + nb*16 + lo16;
    bv[nb] = bias[c];
    gv[nb]  = do_ln ? g[c]  : 1.f;
    bbv[nb] = do_ln ? bb[c] : 0.f;
  }
  #pragma unroll
  for (int mb=0;mb<4;++mb){
    #pragma unroll
    for (int nb=0;nb<4;++nb){
      #pragma unroll
      for (int r=0;r<4;++r) acc[mb][nb][r] = (acc[mb][nb][r] + bv[nb]) * scale;
    }
  }

  if (do_ln){
    #pragma unroll
    for (int mb=0;mb<4;++mb){
      #pragma unroll
      for (int r=0;r<4;++r){
        float s=0.f, ss=0.f;
        #pragma unroll
        for (int nb=0;nb<4;++nb){ float v = acc[mb][nb][r]; s += v; ss += v*v; }
        #pragma unroll
        for (int m=1;m<16;m<<=1){ s += __shfl_xor(s, m, 64); ss += __shfl_xor(ss, m, 64); }
        if (lo16 == 0){
          int row = m0 + mb*16 + hi4*4 + r;
          red[row*8 + wn]     = s;
          red[row*8 + 4 + wn] = ss;
        }
      }
    }
    __syncthreads();
    if (tid < 128){
      float s  = red[tid*8+0]+red[tid*8+1]+red[tid*8+2]+red[tid*8+3];
      float ss = red[tid*8+4]+red[tid*8+5]+red[tid*8+6]+red[tid*8+7];
      float mu = s * (1.f/256.f);
      float var = ss * (1.f/256.f) - mu*mu;
      st[tid*2]   = mu;
      st[tid*2+1] = rsqrtf(var + 1e-5f);
    }
    __syncthreads();
  }

  #pragma unroll
  for (int mb=0;mb<4;++mb){
    #pragma unroll
    for (int r=0;r<4;++r){
      int row = m0 + mb*16 + hi4*4 + r;
      float mu = 0.f, rs = 1.f;
      if (do_ln){ mu = st[row*2]; rs = st[row*2+1]; }
      #pragma unroll
      for (int nb=0;nb<4;++nb){
        int c = n0 + nb*16 + lo16;
        float v = acc[mb][nb][r];
        if (do_ln) v = (v - mu) * rs * gv[nb] + bbv[nb];
        if (do_relu) v = fmaxf(v, 0.f);
        out[(b0 + row)*256 + c] = v;
      }
    }
  }
}

// ---------------------------------------------------------------------------
__global__ __launch_bounds__(256)
void k3_softmax(const float* __restrict__ scores, float* __restrict__ wts)
{
  const int b = blockIdx.x, t = threadIdx.x;
  const int wid = t >> 6, lane = t & 63;
  __shared__ float r4[4];
  float sc[4];
  #pragma unroll
  for (int n=0;n<4;++n) sc[n] = scores[(b*4 + n)*256 + t];
  float wsum = 0.f;
  for (int n=0;n<4;++n){
    float m = sc[n];
    #pragma unroll
    for (int k=1;k<64;k<<=1) m = fmaxf(m, __shfl_xor(m, k, 64));
    if (lane == 0) r4[wid] = m;
    __syncthreads();
    m = fmaxf(fmaxf(r4[0], r4[1]), fmaxf(r4[2], r4[3]));
    __syncthreads();
    float ex = __expf(sc[n] - m);
    float s = ex;
    #pragma unroll
    for (int k=1;k<64;k<<=1) s += __shfl_xor(s, k, 64);
    if (lane == 0) r4[wid] = s;
    __syncthreads();
    s = r4[0] + r4[1] + r4[2] + r4[3];
    __syncthreads();
    wsum += ex / s;
  }
  wts[b*256 + t] = wsum * 0.25f;
}

// ---------------------------------------------------------------------------
// k4a: the reference einsum is 'beh,eh->bh' with weights of SHAPE (B,E) —
// since B=E=H it binds weights[e_axis=batch-index, h_axis=expert-index]:
//   combined[b,h] = sum_e eo[b,e,h] * wts_flat[e*256 + h]   (b-independent W!)
// This is what the reference literally computes; replicate it exactly.
// ---------------------------------------------------------------------------
__global__ __launch_bounds__(256)
void k4a_combined(const float* __restrict__ eo, const float* __restrict__ wts,
                  float* __restrict__ cmb)
{
  const int b = blockIdx.x, t = threadIdx.x;
  const float* p = eo + b*65536 + t;
  float c = 0.f;
  #pragma unroll 8
  for (int e2 = 0; e2 < 256; ++e2) c += p[e2*256] * wts[e2*256 + t];
  cmb[b*256 + t] = c;
}

extern "C" void kernel_launch(void* const* d_in, const int* in_sizes, int n_in,
                              void* d_out, int out_size, void* d_ws, size_t ws_size,
                              hipStream_t stream)
{
  const float* x    = (const float*)d_in[0];
  const float* te   = (const float*)d_in[1];
  const float* W1   = (const float*)d_in[2];
  const float* b1   = (const float*)d_in[3];
  const float* g1   = (const float*)d_in[4];
  const float* bb1  = (const float*)d_in[5];
  const float* W2   = (const float*)d_in[6];
  const float* b2   = (const float*)d_in[7];
  const float* ipw  = (const float*)d_in[8];
  const float* ipb  = (const float*)d_in[9];
  const float* cw   = (const float*)d_in[10];
  const float* cb   = (const float*)d_in[11];
  const float* cg   = (const float*)d_in[12];
  const float* cbt  = (const float*)d_in[13];

  float* out    = (float*)d_out;        // (256,256)
  float* wts    = out + 65536;          // (256,1,256)
  float* eo     = out + 131072;         // (256,256,256)
  float* ws     = (float*)d_ws;
  float* q      = ws;                   // 65536 f32
  float* scores = ws + 65536;           // 262144 f32 (B,4,E)
  float* cmb    = ws + 65536 + 262144;  // 65536 f32

  // q = (te @ Wq^T + bq) / 8
  k_mini<<<2, 512, 0, stream>>>(te, ipw, ipb, 0.125f, 0, nullptr, nullptr, 0, q);
  // per-expert fused chain -> eo (out) + scores
  k2_fused<<<dim3(2, 256), 512, 0, stream>>>(x, W1, b1, g1, bb1, W2, b2, ipw, ipb,
                                             q, eo, scores);
  // softmax over experts, mean over heads -> weights (out)
  k3_softmax<<<256, 256, 0, stream>>>(scores, wts);
  // combined[b,h] = sum_e eo[b,e,h] * wts[e,h]  (reference's literal einsum)
  k4a_combined<<<256, 256, 0, stream>>>(eo, wts, cmb);
  // out = relu(LN(combined @ cw^T + cb))
  k_mini<<<2, 512, 0, stream>>>(cmb, cw, cb, 1.0f, 1, cg, cbt, 1, out);
}

// Round 4
// 200.047 us; speedup vs baseline: 1.0209x; 1.0209x over previous
//
#include <hip/hip_runtime.h>

typedef __bf16 bf16_t;
typedef bf16_t bf16x8 __attribute__((ext_vector_type(8)));
typedef float f32x4 __attribute__((ext_vector_type(4)));

#define MFMA(a,b,c) __builtin_amdgcn_mfma_f32_16x16x32_bf16(a,b,c,0,0,0)

__device__ __forceinline__ void split8(float4 a, float4 b, bf16x8& hi, bf16x8& lo){
  float v[8] = {a.x,a.y,a.z,a.w,b.x,b.y,b.z,b.w};
  #pragma unroll
  for (int i=0;i<8;++i){
    bf16_t h = (bf16_t)v[i];
    hi[i] = h;
    lo[i] = (bf16_t)(v[i] - (float)h);
  }
}

__device__ __forceinline__ bf16x8 cvt8(float4 a, float4 b){
  bf16x8 r;
  r[0]=(bf16_t)a.x; r[1]=(bf16_t)a.y; r[2]=(bf16_t)a.z; r[3]=(bf16_t)a.w;
  r[4]=(bf16_t)b.x; r[5]=(bf16_t)b.y; r[6]=(bf16_t)b.z; r[7]=(bf16_t)b.w;
  return r;
}

// Stage rows x 256 f32 -> LDS bf16 hi+lo, [row][256], per-row XOR swizzle on
// 16B chunks: chunk' = chunk ^ (row&7). Row pitch 512B.
template<int NT>
__device__ __forceinline__ void stage_split(const float* __restrict__ src,
                                            char* dstH, char* dstL, int rows, int tid){
  const int nchunk = rows * 32;
  const float4* s4 = reinterpret_cast<const float4*>(src);
  for (int cid = tid; cid < nchunk; cid += NT){
    int r = cid >> 5, c = cid & 31;
    bf16x8 hi, lo;
    split8(s4[cid*2], s4[cid*2+1], hi, lo);
    int off = r*512 + ((c ^ (r&7))<<4);
    *reinterpret_cast<bf16x8*>(dstH + off) = hi;
    *reinterpret_cast<bf16x8*>(dstL + off) = lo;
  }
}

__device__ __forceinline__ bf16x8 ldsA(const char* buf, int row, int c16){
  return *reinterpret_cast<const bf16x8*>(buf + row*512 + ((c16 ^ (row&7))<<4));
}

// 64x32 C tile (rows 0..63 of LDS A, cols n0..n0+31 of W^T), K=256, split
// precision: acc += Ah*Bh + Ah*Bl + Al*Bh. Each wave owns a DISTINCT n0 ->
// no duplicated W loads across waves.
__device__ __forceinline__ void gemm_split64(f32x4 acc[4][2], const char* bufH,
    const char* bufL, const float* __restrict__ W, int n0, int lo16, int hi4){
  #pragma unroll
  for (int kb = 0; kb < 8; ++kb){
    bf16x8 ah[4], al[4], bh[2], bl[2];
    #pragma unroll
    for (int mb = 0; mb < 4; ++mb){
      ah[mb] = ldsA(bufH, mb*16 + lo16, kb*4 + hi4);
      al[mb] = ldsA(bufL, mb*16 + lo16, kb*4 + hi4);
    }
    #pragma unroll
    for (int nb = 0; nb < 2; ++nb){
      const float4* p = reinterpret_cast<const float4*>(W + ((n0 + nb*16 + lo16)<<8) + kb*32 + hi4*8);
      split8(p[0], p[1], bh[nb], bl[nb]);
    }
    #pragma unroll
    for (int mb = 0; mb < 4; ++mb){
      #pragma unroll
      for (int nb = 0; nb < 2; ++nb){
        acc[mb][nb] = MFMA(ah[mb], bh[nb], acc[mb][nb]);
        acc[mb][nb] = MFMA(ah[mb], bl[nb], acc[mb][nb]);
        acc[mb][nb] = MFMA(al[mb], bh[nb], acc[mb][nb]);
      }
    }
  }
}

// bf16-single variant (scores GEMM only)
__device__ __forceinline__ void gemm_single64(f32x4 acc[4][2], const char* bufH,
    const float* __restrict__ W, int n0, int lo16, int hi4){
  #pragma unroll
  for (int kb = 0; kb < 8; ++kb){
    bf16x8 af[4], bfr[2];
    #pragma unroll
    for (int mb = 0; mb < 4; ++mb) af[mb] = ldsA(bufH, mb*16 + lo16, kb*4 + hi4);
    #pragma unroll
    for (int nb = 0; nb < 2; ++nb){
      const float4* p = reinterpret_cast<const float4*>(W + ((n0 + nb*16 + lo16)<<8) + kb*32 + hi4*8);
      bfr[nb] = cvt8(p[0], p[1]);
    }
    #pragma unroll
    for (int mb = 0; mb < 4; ++mb){
      #pragma unroll
      for (int nb = 0; nb < 2; ++nb) acc[mb][nb] = MFMA(af[mb], bfr[nb], acc[mb][nb]);
    }
  }
}

// ---------------------------------------------------------------------------
// k2_fused: per (expert e, 64-row batch tile):
//   h = x@W1[e]^T + b1 ; LN ; relu -> hr ; eo = hr@W2[e]^T + b2 -> global+LDS
//   k = eo@Wk^T + bk ; scores[b,n,e] = q[b,n*64:].k
// grid (4,256), block 512 = 8 waves, wave wid owns cols [wid*32, wid*32+32).
// LDS ~70KB -> 2 blocks/CU resident (the round-3 kernel's 136KB allowed 1).
// ---------------------------------------------------------------------------
__global__ __launch_bounds__(512, 4)
void k2_fused(const float* __restrict__ x, const float* __restrict__ W1,
              const float* __restrict__ b1, const float* __restrict__ g1,
              const float* __restrict__ bb1, const float* __restrict__ W2,
              const float* __restrict__ b2, const float* __restrict__ ipw,
              const float* __restrict__ ipb, const float* __restrict__ q,
              float* __restrict__ eo_out, float* __restrict__ scores)
{
  __shared__ char lds[70144];
  char* bufH = lds;                      // 32KB: x_hi -> hr_hi -> eo(bf16)
  char* bufL = lds + 32768;              // 32KB: x_lo -> hr_lo
  float* red = (float*)(lds + 65536);    // [64][16] = 4KB
  float* st  = (float*)(lds + 69632);    // [64][2]  = 512B

  const int e  = blockIdx.y;
  const int b0 = blockIdx.x * 64;
  const int tid = threadIdx.x;
  const int lane = tid & 63, wid = tid >> 6;
  const int lo16 = lane & 15, hi4 = lane >> 4;
  const int n0 = wid * 32;

  stage_split<512>(x + b0*256, bufH, bufL, 64, tid);
  __syncthreads();

  f32x4 acc[4][2];
  #pragma unroll
  for (int mb=0;mb<4;++mb){
    #pragma unroll
    for (int nb=0;nb<2;++nb) acc[mb][nb] = (f32x4)0.0f;
  }

  gemm_split64(acc, bufH, bufL, W1 + e*65536, n0, lo16, hi4);

  float b1v[2], g1v[2], bbv[2];
  #pragma unroll
  for (int nb=0;nb<2;++nb){
    int c = n0 + nb*16 + lo16;
    b1v[nb] = b1[e*256 + c];
    g1v[nb] = g1[e*256 + c];
    bbv[nb] = bb1[e*256 + c];
  }
  #pragma unroll
  for (int mb=0;mb<4;++mb){
    #pragma unroll
    for (int nb=0;nb<2;++nb){
      #pragma unroll
      for (int r=0;r<4;++r) acc[mb][nb][r] += b1v[nb];
    }
  }

  // LN stats: per-row sum/sumsq across the 8 column-waves
  #pragma unroll
  for (int mb=0;mb<4;++mb){
    #pragma unroll
    for (int r=0;r<4;++r){
      float s=0.f, ss=0.f;
      #pragma unroll
      for (int nb=0;nb<2;++nb){ float v = acc[mb][nb][r]; s += v; ss += v*v; }
      #pragma unroll
      for (int m=1;m<16;m<<=1){ s += __shfl_xor(s, m, 64); ss += __shfl_xor(ss, m, 64); }
      if (lo16 == 0){
        int row = mb*16 + hi4*4 + r;
        red[row*16 + wid]     = s;
        red[row*16 + 8 + wid] = ss;
      }
    }
  }
  __syncthreads();
  if (tid < 64){
    float s  = 0.f, ss = 0.f;
    #pragma unroll
    for (int i=0;i<8;++i){ s += red[tid*16 + i]; ss += red[tid*16 + 8 + i]; }
    float mu = s * (1.f/256.f);
    float var = ss * (1.f/256.f) - mu*mu;
    st[tid*2]   = mu;
    st[tid*2+1] = rsqrtf(var + 1e-5f);
  }
  __syncthreads();

  // LN + relu -> hr (split bf16) back into bufH/bufL
  #pragma unroll
  for (int mb=0;mb<4;++mb){
    #pragma unroll
    for (int r=0;r<4;++r){
      int row = mb*16 + hi4*4 + r;
      float mu = st[row*2], rs = st[row*2+1];
      #pragma unroll
      for (int nb=0;nb<2;++nb){
        int c = n0 + nb*16 + lo16;
        float v = (acc[mb][nb][r] - mu) * rs * g1v[nb] + bbv[nb];
        v = fmaxf(v, 0.f);
        int off = row*512 + (((c>>3) ^ (row&7))<<4) + (c&7)*2;
        bf16_t h = (bf16_t)v;
        *reinterpret_cast<bf16_t*>(bufH + off) = h;
        *reinterpret_cast<bf16_t*>(bufL + off) = (bf16_t)(v - (float)h);
      }
    }
  }
  __syncthreads();

  // GEMM2: eo = hr @ W2[e]^T + b2
  #pragma unroll
  for (int mb=0;mb<4;++mb){
    #pragma unroll
    for (int nb=0;nb<2;++nb) acc[mb][nb] = (f32x4)0.0f;
  }
  gemm_split64(acc, bufH, bufL, W2 + e*65536, n0, lo16, hi4);

  float b2v[2];
  #pragma unroll
  for (int nb=0;nb<2;++nb) b2v[nb] = b2[e*256 + n0 + nb*16 + lo16];

  __syncthreads();  // all waves done reading hr before eo overwrites bufH

  #pragma unroll
  for (int mb=0;mb<4;++mb){
    #pragma unroll
    for (int r=0;r<4;++r){
      int row = mb*16 + hi4*4 + r;
      int b = b0 + row;
      #pragma unroll
      for (int nb=0;nb<2;++nb){
        int c = n0 + nb*16 + lo16;
        float v = acc[mb][nb][r] + b2v[nb];
        eo_out[(b*256 + e)*256 + c] = v;
        int off = row*512 + (((c>>3) ^ (row&7))<<4) + (c&7)*2;
        *reinterpret_cast<bf16_t*>(bufH + off) = (bf16_t)v;
      }
    }
  }
  __syncthreads();

  // GEMM3: k = eo @ Wk^T + bk ; scores = q . k per head (head = wid>>1)
  #pragma unroll
  for (int mb=0;mb<4;++mb){
    #pragma unroll
    for (int nb=0;nb<2;++nb) acc[mb][nb] = (f32x4)0.0f;
  }
  gemm_single64(acc, bufH, ipw + 65536, n0, lo16, hi4);

  float bkv[2];
  #pragma unroll
  for (int nb=0;nb<2;++nb) bkv[nb] = ipb[256 + n0 + nb*16 + lo16];

  #pragma unroll
  for (int mb=0;mb<4;++mb){
    #pragma unroll
    for (int r=0;r<4;++r){
      int row = mb*16 + hi4*4 + r;
      int b = b0 + row;
      float p = 0.f;
      #pragma unroll
      for (int nb=0;nb<2;++nb){
        int c = n0 + nb*16 + lo16;
        p += q[b*256 + c] * (acc[mb][nb][r] + bkv[nb]);
      }
      #pragma unroll
      for (int m=1;m<16;m<<=1) p += __shfl_xor(p, m, 64);
      if (lo16 == 0) red[row*16 + wid] = p;   // partial over 32 cols
    }
  }
  __syncthreads();
  if (tid < 256){
    int row = tid >> 2, hd = tid & 3;
    float sc = red[row*16 + hd*2] + red[row*16 + hd*2 + 1];
    scores[((b0 + row)*4 + hd)*256 + e] = sc;
  }
}

// ---------------------------------------------------------------------------
// k_mini: out = act( maybeLN( (A @ W^T + bias) * scale ) ), 256x256x256,
// split-precision GEMM. grid 2, block 512. (few-µs kernels; unchanged)
// ---------------------------------------------------------------------------
__device__ __forceinline__ void gemm_split128(f32x4 acc[4][4], const char* bufH,
    const char* bufL, const float* __restrict__ W, int m0, int n0, int lo16, int hi4){
  #pragma unroll
  for (int kb = 0; kb < 8; ++kb){
    bf16x8 ah[4], al[4], bh[4], bl[4];
    #pragma unroll
    for (int mb = 0; mb < 4; ++mb){
      ah[mb] = ldsA(bufH, m0 + mb*16 + lo16, kb*4 + hi4);
      al[mb] = ldsA(bufL, m0 + mb*16 + lo16, kb*4 + hi4);
    }
    #pragma unroll
    for (int nb = 0; nb < 4; ++nb){
      const float4* p = reinterpret_cast<const float4*>(W + ((n0 + nb*16 + lo16)<<8) + kb*32 + hi4*8);
      split8(p[0], p[1], bh[nb], bl[nb]);
    }
    #pragma unroll
    for (int mb = 0; mb < 4; ++mb){
      #pragma unroll
      for (int nb = 0; nb < 4; ++nb){
        acc[mb][nb] = MFMA(ah[mb], bh[nb], acc[mb][nb]);
        acc[mb][nb] = MFMA(ah[mb], bl[nb], acc[mb][nb]);
        acc[mb][nb] = MFMA(al[mb], bh[nb], acc[mb][nb]);
      }
    }
  }
}

__global__ __launch_bounds__(512, 2)
void k_mini(const float* __restrict__ A, const float* __restrict__ W,
            const float* __restrict__ bias, float scale, int do_ln,
            const float* __restrict__ g, const float* __restrict__ bb,
            int do_relu, float* __restrict__ out)
{
  __shared__ char lds[136192];
  char* bufH = lds;
  char* bufL = lds + 65536;
  float* red = (float*)(lds + 131072);
  float* st  = (float*)(lds + 135168);

  const int b0 = blockIdx.x * 128;
  const int tid = threadIdx.x;
  const int lane = tid & 63, wid = tid >> 6;
  const int lo16 = lane & 15, hi4 = lane >> 4;
  const int wm = wid >> 2, wn = wid & 3;
  const int m0 = wm * 64, n0 = wn * 64;

  stage_split<512>(A + b0*256, bufH, bufL, 128, tid);
  __syncthreads();

  f32x4 acc[4][4];
  #pragma unroll
  for (int mb=0;mb<4;++mb){
    #pragma unroll
    for (int nb=0;nb<4;++nb) acc[mb][nb] = (f32x4)0.0f;
  }
  gemm_split128(acc, bufH, bufL, W, m0, n0, lo16, hi4);

  float bv[4], gv[4], bbv[4];
  #pragma unroll
  for (int nb=0;nb<4;++nb){
    int c = n0 + nb*16 + lo16;
    bv[nb] = bias[c];
    gv[nb]  = do_ln ? g[c]  : 1.f;
    bbv[nb] = do_ln ? bb[c] : 0.f;
  }
  #pragma unroll
  for (int mb=0;mb<4;++mb){
    #pragma unroll
    for (int nb=0;nb<4;++nb){
      #pragma unroll
      for (int r=0;r<4;++r) acc[mb][nb][r] = (acc[mb][nb][r] + bv[nb]) * scale;
    }
  }

  if (do_ln){
    #pragma unroll
    for (int mb=0;mb<4;++mb){
      #pragma unroll
      for (int r=0;r<4;++r){
        float s=0.f, ss=0.f;
        #pragma unroll
        for (int nb=0;nb<4;++nb){ float v = acc[mb][nb][r]; s += v; ss += v*v; }
        #pragma unroll
        for (int m=1;m<16;m<<=1){ s += __shfl_xor(s, m, 64); ss += __shfl_xor(ss, m, 64); }
        if (lo16 == 0){
          int row = m0 + mb*16 + hi4*4 + r;
          red[row*8 + wn]     = s;
          red[row*8 + 4 + wn] = ss;
        }
      }
    }
    __syncthreads();
    if (tid < 128){
      float s  = red[tid*8+0]+red[tid*8+1]+red[tid*8+2]+red[tid*8+3];
      float ss = red[tid*8+4]+red[tid*8+5]+red[tid*8+6]+red[tid*8+7];
      float mu = s * (1.f/256.f);
      float var = ss * (1.f/256.f) - mu*mu;
      st[tid*2]   = mu;
      st[tid*2+1] = rsqrtf(var + 1e-5f);
    }
    __syncthreads();
  }

  #pragma unroll
  for (int mb=0;mb<4;++mb){
    #pragma unroll
    for (int r=0;r<4;++r){
      int row = m0 + mb*16 + hi4*4 + r;
      float mu = 0.f, rs = 1.f;
      if (do_ln){ mu = st[row*2]; rs = st[row*2+1]; }
      #pragma unroll
      for (int nb=0;nb<4;++nb){
        int c = n0 + nb*16 + lo16;
        float v = acc[mb][nb][r];
        if (do_ln) v = (v - mu) * rs * gv[nb] + bbv[nb];
        if (do_relu) v = fmaxf(v, 0.f);
        out[(b0 + row)*256 + c] = v;
      }
    }
  }
}

// ---------------------------------------------------------------------------
__global__ __launch_bounds__(256)
void k3_softmax(const float* __restrict__ scores, float* __restrict__ wts)
{
  const int b = blockIdx.x, t = threadIdx.x;
  const int wid = t >> 6, lane = t & 63;
  __shared__ float r4[4];
  float sc[4];
  #pragma unroll
  for (int n=0;n<4;++n) sc[n] = scores[(b*4 + n)*256 + t];
  float wsum = 0.f;
  for (int n=0;n<4;++n){
    float m = sc[n];
    #pragma unroll
    for (int k=1;k<64;k<<=1) m = fmaxf(m, __shfl_xor(m, k, 64));
    if (lane == 0) r4[wid] = m;
    __syncthreads();
    m = fmaxf(fmaxf(r4[0], r4[1]), fmaxf(r4[2], r4[3]));
    __syncthreads();
    float ex = __expf(sc[n] - m);
    float s = ex;
    #pragma unroll
    for (int k=1;k<64;k<<=1) s += __shfl_xor(s, k, 64);
    if (lane == 0) r4[wid] = s;
    __syncthreads();
    s = r4[0] + r4[1] + r4[2] + r4[3];
    __syncthreads();
    wsum += ex / s;
  }
  wts[b*256 + t] = wsum * 0.25f;
}

// ---------------------------------------------------------------------------
// k4a: reference's literal einsum 'beh,eh->bh' with weights shape (B,E):
//   combined[b,h] = sum_e eo[b,e,h] * wts_flat[e*256 + h]
// ---------------------------------------------------------------------------
__global__ __launch_bounds__(256)
void k4a_combined(const float* __restrict__ eo, const float* __restrict__ wts,
                  float* __restrict__ cmb)
{
  const int b = blockIdx.x, t = threadIdx.x;
  const float* p = eo + b*65536 + t;
  float c = 0.f;
  #pragma unroll 8
  for (int e2 = 0; e2 < 256; ++e2) c += p[e2*256] * wts[e2*256 + t];
  cmb[b*256 + t] = c;
}

extern "C" void kernel_launch(void* const* d_in, const int* in_sizes, int n_in,
                              void* d_out, int out_size, void* d_ws, size_t ws_size,
                              hipStream_t stream)
{
  const float* x    = (const float*)d_in[0];
  const float* te   = (const float*)d_in[1];
  const float* W1   = (const float*)d_in[2];
  const float* b1   = (const float*)d_in[3];
  const float* g1   = (const float*)d_in[4];
  const float* bb1  = (const float*)d_in[5];
  const float* W2   = (const float*)d_in[6];
  const float* b2   = (const float*)d_in[7];
  const float* ipw  = (const float*)d_in[8];
  const float* ipb  = (const float*)d_in[9];
  const float* cw   = (const float*)d_in[10];
  const float* cb   = (const float*)d_in[11];
  const float* cg   = (const float*)d_in[12];
  const float* cbt  = (const float*)d_in[13];

  float* out    = (float*)d_out;        // (256,256)
  float* wts    = out + 65536;          // (256,1,256)
  float* eo     = out + 131072;         // (256,256,256)
  float* ws     = (float*)d_ws;
  float* q      = ws;                   // 65536 f32
  float* scores = ws + 65536;           // 262144 f32 (B,4,E)
  float* cmb    = ws + 65536 + 262144;  // 65536 f32

  // q = (te @ Wq^T + bq) / 8
  k_mini<<<2, 512, 0, stream>>>(te, ipw, ipb, 0.125f, 0, nullptr, nullptr, 0, q);
  // per-expert fused chain -> eo (out) + scores
  k2_fused<<<dim3(4, 256), 512, 0, stream>>>(x, W1, b1, g1, bb1, W2, b2, ipw, ipb,
                                             q, eo, scores);
  // softmax over experts, mean over heads -> weights (out)
  k3_softmax<<<256, 256, 0, stream>>>(scores, wts);
  // combined[b,h] = sum_e eo[b,e,h] * wts[e,h]
  k4a_combined<<<256, 256, 0, stream>>>(eo, wts, cmb);
  // out = relu(LN(combined @ cw^T + cb))
  k_mini<<<2, 512, 0, stream>>>(cmb, cw, cb, 1.0f, 1, cg, cbt, 1, out);
}